// Round 20
// baseline (40.256 us; speedup 1.0000x reference)
//
#include <hip/hip_runtime.h>
#include <hip/hip_bf16.h>
#include <stdint.h>

// Problem constants (fixed by the reference).
#define M_DIM 8192
#define K_DIM 2048
#define N_DIM 2048

typedef __attribute__((ext_vector_type(8))) short bf16x8;
typedef __attribute__((ext_vector_type(4))) float f32x4;

// fp32 -> bf16 round-to-nearest-even (data has no NaNs).
__device__ __forceinline__ ushort f2bf(float f) {
    union { float f; uint32_t u; } v; v.f = f;
    uint32_t u = v.u;
    uint32_t r = u + 0x7fffu + ((u >> 16) & 1u);
    return (ushort)(r >> 16);
}

typedef const __attribute__((address_space(1))) uint32_t gu32;
typedef __attribute__((address_space(3))) uint32_t lu32;
__device__ __forceinline__ void load_lds16(const void* g, void* l) {
    // 16B per lane, dest = wave-uniform LDS base + lane*16 (HW rule).
    __builtin_amdgcn_global_load_lds((gu32*)g, (lu32*)l, 16, 0, 0);
}

// Workspace images are byte-for-byte LDS images (XOR-swizzled):
//   A image: per tile (rb*32+kt), 8KB: byte(r,k2) = r*128 + (k2 ^ ((r&7)<<4))
//   B image: per (cb,kt), 8KB panel at Btk + cb*256KB + kt*8KB ([cb][kt]:
//            one gemm block's B stream is a contiguous 256KB range).
//
// prep: R9/R17 structure (measured ~15 us, ~= traffic floor).
__global__ __launch_bounds__(256) void prep(const float* __restrict__ A,
                                            const float* __restrict__ B,
                                            char* __restrict__ Btk,
                                            char* __restrict__ Abf,
                                            uint8_t* __restrict__ maskb) {
    __shared__ __align__(16) ushort lds[64][70];
    const int b = blockIdx.x;
    const int t = threadIdx.x;

    if (b < 512) {
        // ---- scan + pack: 8 k-tiles of one row-block quarter ----
        const int rb = b >> 2;
        const int seg = b & 3;
        const int r  = t >> 2;            // row in tile 0..63
        const int cs = (t & 3) << 2;      // float col base {0,4,8,12}; +i*16
        const float* base = A + (size_t)(rb * 64 + r) * K_DIM + seg * 512 + cs;
        const int sw = (r & 7) << 4;
        uint32_t outb = 0;
        float4 cur[4], nxt[4];
#pragma unroll
        for (int i = 0; i < 4; ++i) cur[i] = *(const float4*)(base + i * 16);
#pragma unroll
        for (int it = 0; it < 8; ++it) {
            if (it < 7) {
#pragma unroll
                for (int i = 0; i < 4; ++i) nxt[i] = *(const float4*)(base + (it + 1) * 64 + i * 16);
            }
            bool nz = false;
#pragma unroll
            for (int i = 0; i < 4; ++i)
                nz = nz || (cur[i].x != 0.f) || (cur[i].y != 0.f) ||
                           (cur[i].z != 0.f) || (cur[i].w != 0.f);
            int anynz = __syncthreads_or((int)nz);
            if (anynz) {
                outb |= 1u << it;
                char* dst = Abf + (size_t)(rb * 32 + seg * 8 + it) * 8192 + r * 128;
#pragma unroll
                for (int i = 0; i < 4; ++i) {
                    uint32_t lo = (uint32_t)f2bf(cur[i].x) | ((uint32_t)f2bf(cur[i].y) << 16);
                    uint32_t hi = (uint32_t)f2bf(cur[i].z) | ((uint32_t)f2bf(cur[i].w) << 16);
                    *(uint2*)(dst + ((cs * 2 + i * 32) ^ sw)) = make_uint2(lo, hi);
                }
            }
#pragma unroll
            for (int i = 0; i < 4; ++i) cur[i] = nxt[i];
        }
        if (t == 0) maskb[rb * 4 + seg] = (uint8_t)outb;
    } else {
        // ---- conv: one 64x64 tile of B -> swizzled [cb][kt] image ----
        const int c = b - 512;
        const int cbi = c & 31;           // 64-wide column block 0..31
        const int c0 = cbi * 64;          // N offset
        const int kt = c >> 5;            // 0..31
        const int r0 = kt * 64;           // K offset
        const int r  = t >> 2;
        const int cs = (t & 3) << 2;
#pragma unroll
        for (int i = 0; i < 4; ++i) {
            int cc = cs + i * 16;
            float4 v = *(const float4*)(B + (size_t)(r0 + r) * N_DIM + c0 + cc);
            lds[r][cc + 0] = f2bf(v.x);
            lds[r][cc + 1] = f2bf(v.y);
            lds[r][cc + 2] = f2bf(v.z);
            lds[r][cc + 3] = f2bf(v.w);
        }
        __syncthreads();
        const int ct = t >> 2;            // n within tile, 0..63
        const int s  = (t & 3) * 16;      // k segment base
        uint4 tmpv[2];
        ushort* tmp = (ushort*)tmpv;
#pragma unroll
        for (int j = 0; j < 16; ++j) tmp[j] = lds[s + j][ct];
        char* dst = Btk + (size_t)cbi * 262144 + (size_t)kt * 8192 + ct * 128;
        const int swn = (ct & 7) << 4;
        *(uint4*)(dst + ((s * 2)      ^ swn)) = tmpv[0];
        *(uint4*)(dst + ((s * 2 + 16) ^ swn)) = tmpv[1];
    }
}

// Block-sparse GEMM, 64x64 tile, single-buffered 16KB LDS, 8 blocks/CU,
// 2D XCD partition (R17 base, best 38.0us). ONLY change vs R19: the C-store
// is a PLAIN cached store instead of __builtin_nontemporal_store — A/B test
// of the write path (harness memsets hit 6.8TB/s with cached stores; if NT
// bypasses L2 write-combining at ~2.5-3TB/s it fully explains gemm's 23us).
__global__ __launch_bounds__(256) void gemm_sparse(const char* __restrict__ Abf,
                                                   const char* __restrict__ Btk,
                                                   const uint32_t* __restrict__ mask,
                                                   float* __restrict__ C) {
    // [sA 8K][sB 8K] = 16KB; epilogue reuses [0, 9216) as 4 x 2304B wave regions
    __shared__ __align__(16) char smem[16384];
    char* sA = smem;
    char* sB = smem + 8192;

    const int orig = blockIdx.x;
    const int xcd = orig & 7;                  // round-robin wg->XCD assumption
    const int i0 = orig >> 3;                  // 0..511
    const int cb = (xcd >> 1) * 8 + (i0 & 7);  // 0..31: 8 cols per XCD-pair (B 2MB)
    const int rb = (xcd & 1) * 64 + (i0 >> 3); // 0..127: rb-half per XCD parity (A 1.64MB)
    const int tid = threadIdx.x;
    const int lane = tid & 63;
    const int wid = tid >> 6;
    const int wm = wid >> 1;      // 0..1
    const int wn = wid & 1;       // 0..1

    f32x4 acc[2][2];
#pragma unroll
    for (int i = 0; i < 2; ++i)
#pragma unroll
        for (int j = 0; j < 2; ++j) acc[i][j] = (f32x4){0.f, 0.f, 0.f, 0.f};

    uint32_t m = mask[rb];
    const char* bcol = Btk + (size_t)cb * 262144;   // contiguous B range

    while (m) {
        const int kt = __ffs((int)m) - 1;
        m &= (m - 1);

        // stage B panel (8KB) + A tile (8KB): 4 linear gload_lds per thread
        {
            const char* bt = bcol + (size_t)kt * 8192;
#pragma unroll
            for (int i = 0; i < 2; ++i) {
                const int ch = wid * 2 + i;                 // 0..7, 1KB each
                load_lds16(bt + ch * 1024 + lane * 16, sB + ch * 1024);
            }
            const char* at = Abf + (size_t)(rb * 32 + kt) * 8192;
#pragma unroll
            for (int i = 0; i < 2; ++i) {
                const int ch = wid * 2 + i;
                load_lds16(at + ch * 1024 + lane * 16, sA + ch * 1024);
            }
        }
        __syncthreads();    // drains vmcnt -> staged data visible to all waves

#pragma unroll
        for (int ks = 0; ks < 2; ++ks) {
            bf16x8 af[2], bfr[2];
#pragma unroll
            for (int mf = 0; mf < 2; ++mf) {
                int row = wm * 32 + mf * 16 + (lane & 15);
                int byte = row * 128 + (ks * 32 + (lane >> 4) * 8) * 2;
                byte ^= ((row & 7) << 4);
                af[mf] = *(const bf16x8*)(sA + byte);
            }
#pragma unroll
            for (int nf = 0; nf < 2; ++nf) {
                int row = wn * 32 + nf * 16 + (lane & 15);
                int byte = row * 128 + (ks * 32 + (lane >> 4) * 8) * 2;
                byte ^= ((row & 7) << 4);
                bfr[nf] = *(const bf16x8*)(sB + byte);
            }
#pragma unroll
            for (int mf = 0; mf < 2; ++mf)
#pragma unroll
                for (int nf = 0; nf < 2; ++nf)
                    acc[mf][nf] = __builtin_amdgcn_mfma_f32_16x16x32_bf16(
                        af[mf], bfr[nf], acc[mf][nf], 0, 0, 0);
        }
        __syncthreads();    // buffer consumed -> safe to restage
    }

    // ---- epilogue: per-wave compact 2-pass LDS transpose -> f32x4 stores ----
    // MFMA C/D layout: col=lane&15, row=(lane>>4)*4+reg. Wave-private 16x36-float
    // region (2304B) reused across the two mf halves (DS pipe in-order per wave).
    float* ep = (float*)(smem + wid * 2304);
    const int crow_base = rb * 64 + wm * 32;
    const int ccol_base = cb * 64 + wn * 32;
#pragma unroll
    for (int mf = 0; mf < 2; ++mf) {
#pragma unroll
        for (int nf = 0; nf < 2; ++nf)
#pragma unroll
            for (int j = 0; j < 4; ++j)
                ep[((lane >> 4) * 4 + j) * 36 + nf * 16 + (lane & 15)] = acc[mf][nf][j];
#pragma unroll
        for (int rep = 0; rep < 2; ++rep) {
            int row16 = rep * 8 + (lane >> 3);
            f32x4 v = *(const f32x4*)(ep + row16 * 36 + (lane & 7) * 4);
            float* dst = C + (size_t)(crow_base + mf * 16 + row16) * N_DIM
                         + ccol_base + (lane & 7) * 4;
            *(f32x4*)dst = v;              // plain cached store (A/B vs NT)
        }
    }
}

extern "C" void kernel_launch(void* const* d_in, const int* in_sizes, int n_in,
                              void* d_out, int out_size, void* d_ws, size_t ws_size,
                              hipStream_t stream) {
    const float* A = (const float*)d_in[0];
    const float* B = (const float*)d_in[1];
    float* C = (float*)d_out;

    // Workspace: [0,8MB) Btk image [cb][kt]; [8MB,40MB) Abf images; [40MB,+512) mask
    char* Btk = (char*)d_ws;
    char* Abf = (char*)d_ws + (size_t)8 * 1024 * 1024;
    uint8_t* maskb = (uint8_t*)((char*)d_ws + (size_t)40 * 1024 * 1024);

    prep<<<1536, 256, 0, stream>>>(A, B, Btk, Abf, maskb);
    gemm_sparse<<<(M_DIM / 64) * (N_DIM / 64), 256, 0, stream>>>(
        Abf, Btk, (const uint32_t*)maskb, C);
}

// Round 21
// 37.493 us; speedup vs baseline: 1.0737x; 1.0737x over previous
//
#include <hip/hip_runtime.h>
#include <hip/hip_bf16.h>
#include <stdint.h>

// Problem constants (fixed by the reference).
#define M_DIM 8192
#define K_DIM 2048
#define N_DIM 2048

typedef __attribute__((ext_vector_type(8))) short bf16x8;
typedef __attribute__((ext_vector_type(4))) float f32x4;

// fp32 -> bf16 round-to-nearest-even (data has no NaNs).
__device__ __forceinline__ ushort f2bf(float f) {
    union { float f; uint32_t u; } v; v.f = f;
    uint32_t u = v.u;
    uint32_t r = u + 0x7fffu + ((u >> 16) & 1u);
    return (ushort)(r >> 16);
}

typedef const __attribute__((address_space(1))) uint32_t gu32;
typedef __attribute__((address_space(3))) uint32_t lu32;
__device__ __forceinline__ void load_lds16(const void* g, void* l) {
    // 16B per lane, dest = wave-uniform LDS base + lane*16 (HW rule).
    __builtin_amdgcn_global_load_lds((gu32*)g, (lu32*)l, 16, 0, 0);
}

// Workspace images are byte-for-byte LDS images (XOR-swizzled):
//   A image: per tile (rb*32+kt), 8KB: byte(r,k2) = r*128 + (k2 ^ ((r&7)<<4))
//   B image: per (cb,kt), 8KB panel at Btk + cb*256KB + kt*8KB ([cb][kt]).
//
// prep: R9/R17 structure (measured ~15 us, ~= traffic floor). No reg cap —
// its float4 pipeline needs ~90 VGPRs (R12 lesson: capping prep => spills).
__global__ __launch_bounds__(256) void prep(const float* __restrict__ A,
                                            const float* __restrict__ B,
                                            char* __restrict__ Btk,
                                            char* __restrict__ Abf,
                                            uint8_t* __restrict__ maskb) {
    __shared__ __align__(16) ushort lds[64][70];
    const int b = blockIdx.x;
    const int t = threadIdx.x;

    if (b < 512) {
        // ---- scan + pack: 8 k-tiles of one row-block quarter ----
        const int rb = b >> 2;
        const int seg = b & 3;
        const int r  = t >> 2;            // row in tile 0..63
        const int cs = (t & 3) << 2;      // float col base {0,4,8,12}; +i*16
        const float* base = A + (size_t)(rb * 64 + r) * K_DIM + seg * 512 + cs;
        const int sw = (r & 7) << 4;
        uint32_t outb = 0;
        float4 cur[4], nxt[4];
#pragma unroll
        for (int i = 0; i < 4; ++i) cur[i] = *(const float4*)(base + i * 16);
#pragma unroll
        for (int it = 0; it < 8; ++it) {
            if (it < 7) {
#pragma unroll
                for (int i = 0; i < 4; ++i) nxt[i] = *(const float4*)(base + (it + 1) * 64 + i * 16);
            }
            bool nz = false;
#pragma unroll
            for (int i = 0; i < 4; ++i)
                nz = nz || (cur[i].x != 0.f) || (cur[i].y != 0.f) ||
                           (cur[i].z != 0.f) || (cur[i].w != 0.f);
            int anynz = __syncthreads_or((int)nz);
            if (anynz) {
                outb |= 1u << it;
                char* dst = Abf + (size_t)(rb * 32 + seg * 8 + it) * 8192 + r * 128;
#pragma unroll
                for (int i = 0; i < 4; ++i) {
                    uint32_t lo = (uint32_t)f2bf(cur[i].x) | ((uint32_t)f2bf(cur[i].y) << 16);
                    uint32_t hi = (uint32_t)f2bf(cur[i].z) | ((uint32_t)f2bf(cur[i].w) << 16);
                    *(uint2*)(dst + ((cs * 2 + i * 32) ^ sw)) = make_uint2(lo, hi);
                }
            }
#pragma unroll
            for (int i = 0; i < 4; ++i) cur[i] = nxt[i];
        }
        if (t == 0) maskb[rb * 4 + seg] = (uint8_t)outb;
    } else {
        // ---- conv: one 64x64 tile of B -> swizzled [cb][kt] image ----
        const int c = b - 512;
        const int cbi = c & 31;           // 64-wide column block 0..31
        const int c0 = cbi * 64;          // N offset
        const int kt = c >> 5;            // 0..31
        const int r0 = kt * 64;           // K offset
        const int r  = t >> 2;
        const int cs = (t & 3) << 2;
#pragma unroll
        for (int i = 0; i < 4; ++i) {
            int cc = cs + i * 16;
            float4 v = *(const float4*)(B + (size_t)(r0 + r) * N_DIM + c0 + cc);
            lds[r][cc + 0] = f2bf(v.x);
            lds[r][cc + 1] = f2bf(v.y);
            lds[r][cc + 2] = f2bf(v.z);
            lds[r][cc + 3] = f2bf(v.w);
        }
        __syncthreads();
        const int ct = t >> 2;            // n within tile, 0..63
        const int s  = (t & 3) * 16;      // k segment base
        uint4 tmpv[2];
        ushort* tmp = (ushort*)tmpv;
#pragma unroll
        for (int j = 0; j < 16; ++j) tmp[j] = lds[s + j][ct];
        char* dst = Btk + (size_t)cbi * 262144 + (size_t)kt * 8192 + ct * 128;
        const int swn = (ct & 7) << 4;
        *(uint4*)(dst + ((s * 2)      ^ swn)) = tmpv[0];
        *(uint4*)(dst + ((s * 2 + 16) ^ swn)) = tmpv[1];
    }
}

// Block-sparse GEMM, 64x64 tile, single-buffered 16KB LDS, 2D XCD partition,
// NT C-stores (R17 base, best 38.0us). ONLY change: __launch_bounds__(256, 8)
// caps VGPR at 64 so 8 blocks/CU (32 waves) actually materialize — the R15/R17
// "8 blocks/CU" premise was never verified; if the allocator was at 65-128
// VGPR we have been running 4 blocks/CU the whole time.
__global__ __launch_bounds__(256, 8) void gemm_sparse(const char* __restrict__ Abf,
                                                      const char* __restrict__ Btk,
                                                      const uint32_t* __restrict__ mask,
                                                      float* __restrict__ C) {
    // [sA 8K][sB 8K] = 16KB; epilogue reuses [0, 9216) as 4 x 2304B wave regions
    __shared__ __align__(16) char smem[16384];
    char* sA = smem;
    char* sB = smem + 8192;

    const int orig = blockIdx.x;
    const int xcd = orig & 7;                  // round-robin wg->XCD assumption
    const int i0 = orig >> 3;                  // 0..511
    const int cb = (xcd >> 1) * 8 + (i0 & 7);  // 0..31: 8 cols per XCD-pair (B 2MB)
    const int rb = (xcd & 1) * 64 + (i0 >> 3); // 0..127: rb-half per XCD parity (A 1.64MB)
    const int tid = threadIdx.x;
    const int lane = tid & 63;
    const int wid = tid >> 6;
    const int wm = wid >> 1;      // 0..1
    const int wn = wid & 1;       // 0..1

    f32x4 acc[2][2];
#pragma unroll
    for (int i = 0; i < 2; ++i)
#pragma unroll
        for (int j = 0; j < 2; ++j) acc[i][j] = (f32x4){0.f, 0.f, 0.f, 0.f};

    uint32_t m = mask[rb];
    const char* bcol = Btk + (size_t)cb * 262144;   // contiguous B range

    while (m) {
        const int kt = __ffs((int)m) - 1;
        m &= (m - 1);

        // stage B panel (8KB) + A tile (8KB): 4 linear gload_lds per thread
        {
            const char* bt = bcol + (size_t)kt * 8192;
#pragma unroll
            for (int i = 0; i < 2; ++i) {
                const int ch = wid * 2 + i;                 // 0..7, 1KB each
                load_lds16(bt + ch * 1024 + lane * 16, sB + ch * 1024);
            }
            const char* at = Abf + (size_t)(rb * 32 + kt) * 8192;
#pragma unroll
            for (int i = 0; i < 2; ++i) {
                const int ch = wid * 2 + i;
                load_lds16(at + ch * 1024 + lane * 16, sA + ch * 1024);
            }
        }
        __syncthreads();    // drains vmcnt -> staged data visible to all waves

#pragma unroll
        for (int ks = 0; ks < 2; ++ks) {
            bf16x8 af[2], bfr[2];
#pragma unroll
            for (int mf = 0; mf < 2; ++mf) {
                int row = wm * 32 + mf * 16 + (lane & 15);
                int byte = row * 128 + (ks * 32 + (lane >> 4) * 8) * 2;
                byte ^= ((row & 7) << 4);
                af[mf] = *(const bf16x8*)(sA + byte);
            }
#pragma unroll
            for (int nf = 0; nf < 2; ++nf) {
                int row = wn * 32 + nf * 16 + (lane & 15);
                int byte = row * 128 + (ks * 32 + (lane >> 4) * 8) * 2;
                byte ^= ((row & 7) << 4);
                bfr[nf] = *(const bf16x8*)(sB + byte);
            }
#pragma unroll
            for (int mf = 0; mf < 2; ++mf)
#pragma unroll
                for (int nf = 0; nf < 2; ++nf)
                    acc[mf][nf] = __builtin_amdgcn_mfma_f32_16x16x32_bf16(
                        af[mf], bfr[nf], acc[mf][nf], 0, 0, 0);
        }
        __syncthreads();    // buffer consumed -> safe to restage
    }

    // ---- epilogue: per-wave compact 2-pass LDS transpose -> f32x4 NT stores ----
    // MFMA C/D layout: col=lane&15, row=(lane>>4)*4+reg. Wave-private 16x36-float
    // region (2304B) reused across the two mf halves (DS pipe in-order per wave).
    float* ep = (float*)(smem + wid * 2304);
    const int crow_base = rb * 64 + wm * 32;
    const int ccol_base = cb * 64 + wn * 32;
#pragma unroll
    for (int mf = 0; mf < 2; ++mf) {
#pragma unroll
        for (int nf = 0; nf < 2; ++nf)
#pragma unroll
            for (int j = 0; j < 4; ++j)
                ep[((lane >> 4) * 4 + j) * 36 + nf * 16 + (lane & 15)] = acc[mf][nf][j];
#pragma unroll
        for (int rep = 0; rep < 2; ++rep) {
            int row16 = rep * 8 + (lane >> 3);
            f32x4 v = *(const f32x4*)(ep + row16 * 36 + (lane & 7) * 4);
            float* dst = C + (size_t)(crow_base + mf * 16 + row16) * N_DIM
                         + ccol_base + (lane & 7) * 4;
            __builtin_nontemporal_store(v, (f32x4*)dst);
        }
    }
}

extern "C" void kernel_launch(void* const* d_in, const int* in_sizes, int n_in,
                              void* d_out, int out_size, void* d_ws, size_t ws_size,
                              hipStream_t stream) {
    const float* A = (const float*)d_in[0];
    const float* B = (const float*)d_in[1];
    float* C = (float*)d_out;

    // Workspace: [0,8MB) Btk image [cb][kt]; [8MB,40MB) Abf images; [40MB,+512) mask
    char* Btk = (char*)d_ws;
    char* Abf = (char*)d_ws + (size_t)8 * 1024 * 1024;
    uint8_t* maskb = (uint8_t*)((char*)d_ws + (size_t)40 * 1024 * 1024);

    prep<<<1536, 256, 0, stream>>>(A, B, Btk, Abf, maskb);
    gemm_sparse<<<(M_DIM / 64) * (N_DIM / 64), 256, 0, stream>>>(
        Abf, Btk, (const uint32_t*)maskb, C);
}